// Round 1
// baseline (131.781 us; speedup 1.0000x reference)
//
#include <hip/hip_runtime.h>
#include <math.h>

// Problem constants (match reference)
constexpr int B_ = 64;
constexpr int Q_ = 300;
constexpr int T_ = 25;
constexpr int NCLS = 91;          // NUM_CLASSES
constexpr int L_ = NCLS + 1;      // 92 classes incl. no-object
constexpr float C_CLS = 1.0f, C_BB = 5.0f, C_GI = 2.0f;
constexpr float W_CE = 2.0f, W_BBOX = 2.5f, W_GIOU = 2.0f;
constexpr float EOS = 0.1f;

__device__ __forceinline__ void cxcywh2xyxy(const float b[4], float o[4]) {
    o[0] = b[0] - 0.5f * b[2];
    o[1] = b[1] - 0.5f * b[3];
    o[2] = b[0] + 0.5f * b[2];
    o[3] = b[1] + 0.5f * b[3];
}

// ---------------------------------------------------------------------------
// Kernel 1: per-(b,q) log-softmax normalizer + transposed cost matrix
// costT[b][t][q] = 5*L1 + 1*(-logprob) + 2*(-giou)
// ---------------------------------------------------------------------------
__global__ void cost_kernel(const float* __restrict__ logits,
                            const float* __restrict__ pboxes,
                            const int*   __restrict__ tlabels,
                            const float* __restrict__ tboxes,
                            float* __restrict__ costT,
                            float* __restrict__ lse) {
    int idx = blockIdx.x * blockDim.x + threadIdx.x;
    if (idx >= B_ * Q_) return;
    int b = idx / Q_;

    const float* lrow = logits + (size_t)idx * L_;
    float mx = lrow[0];
    for (int c = 1; c < L_; ++c) mx = fmaxf(mx, lrow[c]);
    float s = 0.f;
    for (int c = 0; c < L_; ++c) s += expf(lrow[c] - mx);
    float lz = mx + logf(s);
    lse[idx] = lz;

    float pb[4];
    for (int k = 0; k < 4; ++k) pb[k] = pboxes[(size_t)idx * 4 + k];
    float px[4];
    cxcywh2xyxy(pb, px);
    float parea = (px[2] - px[0]) * (px[3] - px[1]);

    int q = idx % Q_;
    for (int t = 0; t < T_; ++t) {
        int lab = tlabels[b * T_ + t];
        float tb[4];
        for (int k = 0; k < 4; ++k) tb[k] = tboxes[(size_t)(b * T_ + t) * 4 + k];

        float cls = lz - lrow[lab];  // -log_softmax[lab]
        float l1 = fabsf(pb[0] - tb[0]) + fabsf(pb[1] - tb[1]) +
                   fabsf(pb[2] - tb[2]) + fabsf(pb[3] - tb[3]);

        float tx[4];
        cxcywh2xyxy(tb, tx);
        float tarea = (tx[2] - tx[0]) * (tx[3] - tx[1]);
        float ltx = fmaxf(px[0], tx[0]), lty = fmaxf(px[1], tx[1]);
        float rbx = fminf(px[2], tx[2]), rby = fminf(px[3], tx[3]);
        float iw = fmaxf(rbx - ltx, 0.f), ih = fmaxf(rby - lty, 0.f);
        float inter = iw * ih;
        float uni = parea + tarea - inter;
        float iou = inter / uni;
        float lix = fminf(px[0], tx[0]), liy = fminf(px[1], tx[1]);
        float rix = fmaxf(px[2], tx[2]), riy = fmaxf(px[3], tx[3]);
        float aw = fmaxf(rix - lix, 0.f), ah = fmaxf(riy - liy, 0.f);
        float ai = aw * ah;
        float giou = iou - (ai - uni) / ai;

        float cost = C_BB * l1 + C_CLS * cls + C_GI * (-giou);
        costT[((size_t)b * T_ + t) * Q_ + q] = cost;
    }
}

// ---------------------------------------------------------------------------
// Kernel 2: Jonker-Volgenant shortest-augmenting-path per image.
// Transposed problem (rows = 25 targets, cols = 300 queries), f64 like the
// reference's np.float64. One block of 64 lanes per image; O(m) phases are
// lane-parallel with shfl_xor argmin (first-index tie-break = np.argmin).
// Output: match_q[b][t] = query index assigned to target t.
// ---------------------------------------------------------------------------
__global__ __launch_bounds__(64) void jv_kernel(const float* __restrict__ costT,
                                                int* __restrict__ match_q) {
    constexpr int N = T_;   // 25 rows
    constexpr int M = Q_;   // 300 cols
    int b = blockIdx.x;
    int tid = threadIdx.x;
    const float* C = costT + (size_t)b * N * M;

    __shared__ double v[M + 1], minv[M + 1], u[N + 1];
    __shared__ int p[M + 1], way[M + 1], used[M + 1];

    for (int j = tid; j <= M; j += 64) { v[j] = 0.0; p[j] = 0; way[j] = 0; }
    for (int i = tid; i <= N; i += 64) u[i] = 0.0;
    __syncthreads();

    for (int i = 1; i <= N; ++i) {
        if (tid == 0) p[0] = i;
        for (int j = tid; j <= M; j += 64) { minv[j] = INFINITY; used[j] = 0; }
        __syncthreads();

        int j0 = 0;
        while (true) {
            if (tid == 0) used[j0] = 1;
            __syncthreads();
            int i0 = p[j0];
            double ui0 = u[i0];
            const float* crow = C + (size_t)(i0 - 1) * M;

            // scan free columns, update minv/way; track lane-local argmin
            double bestv = INFINITY;
            int bestj = M + 1;
            for (int j = tid + 1; j <= M; j += 64) {
                if (!used[j]) {
                    double cur = (double)crow[j - 1] - ui0 - v[j];
                    if (cur < minv[j]) { minv[j] = cur; way[j] = j0; }
                    double mv = minv[j];
                    if (mv < bestv || (mv == bestv && j < bestj)) { bestv = mv; bestj = j; }
                }
            }
            // wave-wide argmin (val, idx) with first-index tie-break
            for (int off = 32; off; off >>= 1) {
                double ov = __shfl_xor(bestv, off);
                int oj = __shfl_xor(bestj, off);
                if (ov < bestv || (ov == bestv && oj < bestj)) { bestv = ov; bestj = oj; }
            }
            int j1 = bestj;
            double delta = bestv;
            __syncthreads();

            // dual updates (distinct u targets per used column; v/minv lane-owned)
            for (int j = tid; j <= M; j += 64) {
                if (used[j]) { u[p[j]] += delta; v[j] -= delta; }
                else { minv[j] -= delta; }
            }
            __syncthreads();

            j0 = j1;
            if (p[j0] == 0) break;
        }

        // augment (short serial chain)
        if (tid == 0) {
            int jj = j0;
            while (jj) {
                int jn = way[jj];
                p[jj] = p[jn];
                jj = jn;
            }
        }
        __syncthreads();
    }

    for (int j = tid + 1; j <= M; j += 64) {
        if (p[j]) match_q[b * N + (p[j] - 1)] = j - 1;
    }
}

// ---------------------------------------------------------------------------
// Kernel 3: losses. Block per image; CE over 300 queries + pair losses over
// 25 matches; block-reduce then f64 atomic accumulation.
// accum[0]=sum(w*nll), accum[1]=sum L1, accum[2]=sum (1-giou)
// ---------------------------------------------------------------------------
__global__ __launch_bounds__(256) void loss_kernel(const float* __restrict__ logits,
                                                   const float* __restrict__ pboxes,
                                                   const int*   __restrict__ tlabels,
                                                   const float* __restrict__ tboxes,
                                                   const float* __restrict__ lse,
                                                   const int*   __restrict__ match_q,
                                                   double* __restrict__ accum) {
    int b = blockIdx.x;
    int tid = threadIdx.x;
    __shared__ int mq[T_], lbl[T_];
    if (tid < T_) {
        mq[tid] = match_q[b * T_ + tid];
        lbl[tid] = tlabels[b * T_ + tid];
    }
    __syncthreads();

    float ce = 0.f, bb = 0.f, gi = 0.f;
    for (int q = tid; q < Q_; q += blockDim.x) {
        int label = NCLS;
        for (int t = 0; t < T_; ++t)
            if (mq[t] == q) label = lbl[t];
        size_t row = (size_t)(b * Q_ + q);
        float nll = lse[row] - logits[row * L_ + label];
        float w = (label == NCLS) ? EOS : 1.0f;
        ce += w * nll;
    }

    if (tid < T_) {
        int q = mq[tid];
        const float* pbp = pboxes + (size_t)(b * Q_ + q) * 4;
        const float* tbp = tboxes + (size_t)(b * T_ + tid) * 4;
        float pb[4], tb[4];
        for (int k = 0; k < 4; ++k) { pb[k] = pbp[k]; tb[k] = tbp[k]; }
        bb = fabsf(pb[0] - tb[0]) + fabsf(pb[1] - tb[1]) +
             fabsf(pb[2] - tb[2]) + fabsf(pb[3] - tb[3]);

        float px[4], tx[4];
        cxcywh2xyxy(pb, px);
        cxcywh2xyxy(tb, tx);
        float parea = (px[2] - px[0]) * (px[3] - px[1]);
        float tarea = (tx[2] - tx[0]) * (tx[3] - tx[1]);
        float ltx = fmaxf(px[0], tx[0]), lty = fmaxf(px[1], tx[1]);
        float rbx = fminf(px[2], tx[2]), rby = fminf(px[3], tx[3]);
        float iw = fmaxf(rbx - ltx, 0.f), ih = fmaxf(rby - lty, 0.f);
        float inter = iw * ih;
        float uni = parea + tarea - inter;
        float iou = inter / uni;
        float lix = fminf(px[0], tx[0]), liy = fminf(px[1], tx[1]);
        float rix = fmaxf(px[2], tx[2]), riy = fmaxf(px[3], tx[3]);
        float aw = fmaxf(rix - lix, 0.f), ah = fmaxf(riy - liy, 0.f);
        float ai = aw * ah;
        float giou = iou - (ai - uni) / ai;
        gi = 1.0f - giou;
    }

    __shared__ float r1[256], r2[256], r3[256];
    r1[tid] = ce; r2[tid] = bb; r3[tid] = gi;
    __syncthreads();
    for (int s = 128; s > 0; s >>= 1) {
        if (tid < s) { r1[tid] += r1[tid + s]; r2[tid] += r2[tid + s]; r3[tid] += r3[tid + s]; }
        __syncthreads();
    }
    if (tid == 0) {
        atomicAdd(&accum[0], (double)r1[0]);
        atomicAdd(&accum[1], (double)r2[0]);
        atomicAdd(&accum[2], (double)r3[0]);
    }
}

// ---------------------------------------------------------------------------
// Kernel 4: finalize
// ---------------------------------------------------------------------------
__global__ void finalize_kernel(const double* __restrict__ accum,
                                float* __restrict__ out) {
    if (threadIdx.x == 0 && blockIdx.x == 0) {
        // w.sum() = 64*25*1.0 + 64*275*0.1 = 3360 ; num_t = 64*25 = 1600
        float lce = W_CE * (float)(accum[0] / 3360.0);
        float lbb = W_BBOX * (float)(accum[1] / 1600.0);
        float lgi = W_GIOU * (float)(accum[2] / 1600.0);
        out[0] = lce;
        out[1] = lbb;
        out[2] = lgi;
        out[3] = lce + lbb + lgi;
    }
}

extern "C" void kernel_launch(void* const* d_in, const int* in_sizes, int n_in,
                              void* d_out, int out_size, void* d_ws, size_t ws_size,
                              hipStream_t stream) {
    const float* logits  = (const float*)d_in[0];   // [B,Q,92] f32
    const float* pboxes  = (const float*)d_in[1];   // [B,Q,4]  f32
    const int*   tlabels = (const int*)d_in[2];     // [B,T]    i32
    const float* tboxes  = (const float*)d_in[3];   // [B,T,4]  f32
    float* out = (float*)d_out;

    char* ws = (char*)d_ws;
    double* accum  = (double*)ws;                                  // 64 B
    float*  costT  = (float*)(ws + 64);                            // B*T*Q f32
    size_t off = 64 + (size_t)B_ * T_ * Q_ * sizeof(float);
    float*  lseb   = (float*)(ws + off);                           // B*Q f32
    off += (size_t)B_ * Q_ * sizeof(float);
    int*    match  = (int*)(ws + off);                             // B*T i32

    hipMemsetAsync(d_ws, 0, 64, stream);

    cost_kernel<<<(B_ * Q_ + 255) / 256, 256, 0, stream>>>(
        logits, pboxes, tlabels, tboxes, costT, lseb);
    jv_kernel<<<B_, 64, 0, stream>>>(costT, match);
    loss_kernel<<<B_, 256, 0, stream>>>(
        logits, pboxes, tlabels, tboxes, lseb, match, accum);
    finalize_kernel<<<1, 64, 0, stream>>>(accum, out);
}

// Round 2
// 86.518 us; speedup vs baseline: 1.5232x; 1.5232x over previous
//
#include <hip/hip_runtime.h>
#include <math.h>

constexpr int B_ = 64;
constexpr int Q_ = 300;
constexpr int T_ = 25;
constexpr int NCLS = 91;
constexpr int L_ = NCLS + 1;       // 92
constexpr float C_BB = 5.0f, C_GI = 2.0f;
constexpr float W_CE = 2.0f, W_BBOX = 2.5f, W_GIOU = 2.0f;
constexpr float EOS = 0.1f;
constexpr int K_ = 5;              // columns per lane (strided; some invalid)

// monotone map f64 -> u64, low 9 bits replaced by column index (tie-break =
// smaller index, matching np.argmin). Truncation perturbs order only for
// gaps < ~4e-12 (abs @ |v|~32) -- measure-zero for f32-derived costs.
__device__ __forceinline__ unsigned long long packkey(double v, int j) {
    long long bb = __double_as_longlong(v);
    unsigned long long u = (unsigned long long)bb;
    u = (bb < 0) ? ~u : (u | 0x8000000000000000ULL);
    return (u & ~511ULL) | (unsigned long long)(unsigned)j;
}

__device__ __forceinline__ float giou_f(const float px[4], float parea,
                                        const float tx[4], float tarea) {
    float ltx = fmaxf(px[0], tx[0]), lty = fmaxf(px[1], tx[1]);
    float rbx = fminf(px[2], tx[2]), rby = fminf(px[3], tx[3]);
    float iw = fmaxf(rbx - ltx, 0.f), ih = fmaxf(rby - lty, 0.f);
    float inter = iw * ih;
    float uni = parea + tarea - inter;
    float iou = inter / uni;
    float lix = fminf(px[0], tx[0]), liy = fminf(px[1], tx[1]);
    float rix = fmaxf(px[2], tx[2]), riy = fmaxf(px[3], tx[3]);
    float aw = fmaxf(rix - lix, 0.f), ah = fmaxf(riy - liy, 0.f);
    float ai = aw * ah;
    return iou - (ai - uni) / ai;
}

__global__ __launch_bounds__(64) void fused_kernel(
        const float* __restrict__ logits,
        const float* __restrict__ pboxes,
        const int*   __restrict__ tlabels,
        const float* __restrict__ tboxes,
        double* __restrict__ accum) {
    const int b = blockIdx.x;
    const int tid = threadIdx.x;

    __shared__ float costL[T_][Q_];     // 30000 B
    __shared__ float lseL[Q_];
    __shared__ int   pL[Q_ + 1];
    __shared__ int   wayL[Q_ + 1];
    __shared__ double uStage[32];
    __shared__ int   mqL[T_];           // matched query per target
    __shared__ int   lblL[T_];
    __shared__ int   lblq[Q_];          // label per query (loss phase)
    __shared__ float tbL[T_][4];        // cxcywh
    __shared__ float txL[T_][4];        // xyxy
    __shared__ float taL[T_];           // area

    // ---- preload targets ----
    if (tid < T_) {
        lblL[tid] = tlabels[b * T_ + tid];
        float c0 = tboxes[(size_t)(b * T_ + tid) * 4 + 0];
        float c1 = tboxes[(size_t)(b * T_ + tid) * 4 + 1];
        float c2 = tboxes[(size_t)(b * T_ + tid) * 4 + 2];
        float c3 = tboxes[(size_t)(b * T_ + tid) * 4 + 3];
        tbL[tid][0] = c0; tbL[tid][1] = c1; tbL[tid][2] = c2; tbL[tid][3] = c3;
        float x0 = c0 - 0.5f * c2, y0 = c1 - 0.5f * c3;
        float x1 = c0 + 0.5f * c2, y1 = c1 + 0.5f * c3;
        txL[tid][0] = x0; txL[tid][1] = y0; txL[tid][2] = x1; txL[tid][3] = y1;
        taL[tid] = (x1 - x0) * (y1 - y0);
    }
    for (int j = tid; j <= Q_; j += 64) { pL[j] = 0; wayL[j] = 0; }
    __syncthreads();

    const float* lgb = logits + (size_t)b * Q_ * L_;
    const float* pbb = pboxes + (size_t)b * Q_ * 4;

    // ---- cost build (into LDS) ----
    for (int q = tid; q < Q_; q += 64) {
        const float4* lr4 = (const float4*)(lgb + (size_t)q * L_);  // 92 = 23*4, 16B aligned
        float m0 = -INFINITY, m1 = -INFINITY, m2 = -INFINITY, m3 = -INFINITY;
        for (int c = 0; c < 23; ++c) {
            float4 v = lr4[c];
            m0 = fmaxf(m0, v.x); m1 = fmaxf(m1, v.y);
            m2 = fmaxf(m2, v.z); m3 = fmaxf(m3, v.w);
        }
        float mx = fmaxf(fmaxf(m0, m1), fmaxf(m2, m3));
        float s0 = 0.f, s1 = 0.f, s2 = 0.f, s3 = 0.f;
        for (int c = 0; c < 23; ++c) {
            float4 v = lr4[c];
            s0 += expf(v.x - mx); s1 += expf(v.y - mx);
            s2 += expf(v.z - mx); s3 += expf(v.w - mx);
        }
        float lz = mx + logf((s0 + s1) + (s2 + s3));
        lseL[q] = lz;

        float p0 = pbb[(size_t)q * 4 + 0], p1 = pbb[(size_t)q * 4 + 1];
        float p2 = pbb[(size_t)q * 4 + 2], p3 = pbb[(size_t)q * 4 + 3];
        float px[4] = { p0 - 0.5f * p2, p1 - 0.5f * p3, p0 + 0.5f * p2, p1 + 0.5f * p3 };
        float parea = (px[2] - px[0]) * (px[3] - px[1]);

        for (int t = 0; t < T_; ++t) {
            float cls = lz - lgb[(size_t)q * L_ + lblL[t]];
            float l1 = fabsf(p0 - tbL[t][0]) + fabsf(p1 - tbL[t][1]) +
                       fabsf(p2 - tbL[t][2]) + fabsf(p3 - tbL[t][3]);
            float tx[4] = { txL[t][0], txL[t][1], txL[t][2], txL[t][3] };
            float g = giou_f(px, parea, tx, taL[t]);
            costL[t][q] = C_BB * l1 + cls - C_GI * g;
        }
    }
    __syncthreads();

    // ---- Jonker-Volgenant (invariant-minv' formulation) ----
    // columns 1..300; lane owns cols tid+1+64k. State in registers.
    double v0[K_], minv[K_], stampv[K_];
    int pReg[K_];
    bool usedk[K_], validk[K_];
#pragma unroll
    for (int k = 0; k < K_; ++k) {
        validk[k] = (tid + 64 * k) < Q_;
        v0[k] = 0.0; pReg[k] = 0; stampv[k] = 0.0;
        usedk[k] = false; minv[k] = INFINITY;
    }
    double u0 = 0.0;   // dual for row `tid` (rows 1..25 live on lanes 1..25)

    for (int i = 1; i <= T_; ++i) {
        if (tid == 0) pL[0] = i;
#pragma unroll
        for (int k = 0; k < K_; ++k) { minv[k] = INFINITY; usedk[k] = false; }
        double S = 0.0;           // cumulative delta this phase
        int j0 = 0, i0 = i;
        double u0i0 = 0.0;        // u[i] == 0 at row i's own phase start

        for (int step = 0; step < 512; ++step) {
            double a = u0i0 - S;
            const float* crow = &costL[i0 - 1][0];
#pragma unroll
            for (int k = 0; k < K_; ++k) {
                if (validk[k] && !usedk[k]) {
                    int col = tid + 64 * k;                  // 0-based
                    double cur = (double)crow[col] - a - v0[k];
                    if (cur < minv[k]) { minv[k] = cur; wayL[col + 1] = j0; }
                }
            }
            unsigned long long best = ~0ULL;
#pragma unroll
            for (int k = 0; k < K_; ++k) {
                if (validk[k] && !usedk[k]) {
                    unsigned long long pk = packkey(minv[k], tid + 1 + 64 * k);
                    if (pk < best) best = pk;
                }
            }
#pragma unroll
            for (int off = 1; off < 64; off <<= 1) {
                unsigned long long o = __shfl_xor(best, off);
                if (o < best) best = o;
            }
            int j1 = (int)(best & 511ULL);
            int owner = (j1 - 1) & 63;
            int k1 = (j1 - 1) >> 6;                          // uniform
            double msel = minv[0]; int psel = pReg[0];
#pragma unroll
            for (int k = 1; k < K_; ++k)
                if (k1 == k) { msel = minv[k]; psel = pReg[k]; }
            double Snew = __shfl(msel, owner);               // exact minv'[j1]
            int i0n = __shfl(psel, owner);
            S = Snew;
            j0 = j1;
            if (i0n == 0) break;                             // augmenting col found
            if (tid == owner) {
#pragma unroll
                for (int k = 0; k < K_; ++k)
                    if (k1 == k) { usedk[k] = true; stampv[k] = Snew; }
            }
            i0 = i0n;
            u0i0 = __shfl(u0, i0);                           // phase-start value (stable)
        }

        // phase-end dual updates (stamp-based, pre-augment p)
#pragma unroll
        for (int k = 0; k < K_; ++k)
            if (validk[k] && usedk[k]) v0[k] -= (S - stampv[k]);
        if (tid < 32) uStage[tid] = 0.0;
        __syncthreads();
#pragma unroll
        for (int k = 0; k < K_; ++k)
            if (validk[k] && usedk[k]) uStage[pReg[k]] = S - stampv[k];
        __syncthreads();
        if (tid >= 1 && tid <= T_) u0 += uStage[tid];
        if (tid == i) u0 += S;                               // virtual column 0
        __syncthreads();
        if (tid == 0) {                                      // augment
            int jj = j0;
            while (jj) { int jn = wayL[jj]; pL[jj] = pL[jn]; jj = jn; }
        }
        __syncthreads();
#pragma unroll
        for (int k = 0; k < K_; ++k)
            if (validk[k]) pReg[k] = pL[tid + 1 + 64 * k];
    }

    // ---- matching -> per-target query, per-query label ----
#pragma unroll
    for (int k = 0; k < K_; ++k)
        if (validk[k] && pReg[k] > 0) mqL[pReg[k] - 1] = tid + 64 * k;
    for (int q = tid; q < Q_; q += 64) lblq[q] = NCLS;
    __syncthreads();
    if (tid < T_) lblq[mqL[tid]] = lblL[tid];
    __syncthreads();

    // ---- losses ----
    double ce = 0.0, sb = 0.0, sg = 0.0;
    for (int q = tid; q < Q_; q += 64) {
        int label = lblq[q];
        float nll = lseL[q] - lgb[(size_t)q * L_ + label];
        float w = (label == NCLS) ? EOS : 1.0f;
        ce += (double)(w * nll);
    }
    if (tid < T_) {
        int q = mqL[tid];
        float p0 = pbb[(size_t)q * 4 + 0], p1 = pbb[(size_t)q * 4 + 1];
        float p2 = pbb[(size_t)q * 4 + 2], p3 = pbb[(size_t)q * 4 + 3];
        sb = (double)(fabsf(p0 - tbL[tid][0]) + fabsf(p1 - tbL[tid][1]) +
                      fabsf(p2 - tbL[tid][2]) + fabsf(p3 - tbL[tid][3]));
        float px[4] = { p0 - 0.5f * p2, p1 - 0.5f * p3, p0 + 0.5f * p2, p1 + 0.5f * p3 };
        float parea = (px[2] - px[0]) * (px[3] - px[1]);
        float tx[4] = { txL[tid][0], txL[tid][1], txL[tid][2], txL[tid][3] };
        float g = giou_f(px, parea, tx, taL[tid]);
        sg = (double)(1.0f - g);
    }
#pragma unroll
    for (int off = 1; off < 64; off <<= 1) {
        ce += __shfl_xor(ce, off);
        sb += __shfl_xor(sb, off);
        sg += __shfl_xor(sg, off);
    }
    if (tid == 0) {
        atomicAdd(&accum[0], ce);
        atomicAdd(&accum[1], sb);
        atomicAdd(&accum[2], sg);
    }
}

__global__ void finalize_kernel(const double* __restrict__ accum,
                                float* __restrict__ out) {
    if (threadIdx.x == 0 && blockIdx.x == 0) {
        // w.sum() = 64*(25*1.0 + 275*0.1) = 3360 ; num_t = 64*25 = 1600
        float lce = W_CE * (float)(accum[0] / 3360.0);
        float lbb = W_BBOX * (float)(accum[1] / 1600.0);
        float lgi = W_GIOU * (float)(accum[2] / 1600.0);
        out[0] = lce;
        out[1] = lbb;
        out[2] = lgi;
        out[3] = lce + lbb + lgi;
    }
}

extern "C" void kernel_launch(void* const* d_in, const int* in_sizes, int n_in,
                              void* d_out, int out_size, void* d_ws, size_t ws_size,
                              hipStream_t stream) {
    (void)in_sizes; (void)n_in; (void)out_size; (void)ws_size;
    const float* logits  = (const float*)d_in[0];   // [B,Q,92] f32
    const float* pboxes  = (const float*)d_in[1];   // [B,Q,4]  f32
    const int*   tlabels = (const int*)d_in[2];     // [B,T]    i32
    const float* tboxes  = (const float*)d_in[3];   // [B,T,4]  f32
    float* out = (float*)d_out;
    double* accum = (double*)d_ws;

    hipMemsetAsync(d_ws, 0, 64, stream);
    fused_kernel<<<B_, 64, 0, stream>>>(logits, pboxes, tlabels, tboxes, accum);
    finalize_kernel<<<1, 64, 0, stream>>>(accum, out);
}

// Round 3
// 80.010 us; speedup vs baseline: 1.6471x; 1.0813x over previous
//
#include <hip/hip_runtime.h>
#include <math.h>

constexpr int B_ = 64;
constexpr int Q_ = 300;
constexpr int T_ = 25;
constexpr int NCLS = 91;
constexpr int L_ = NCLS + 1;       // 92
constexpr float C_BB = 5.0f, C_GI = 2.0f;
constexpr float W_CE = 2.0f, W_BBOX = 2.5f, W_GIOU = 2.0f;
constexpr float EOS = 0.1f;
constexpr int K_ = 5;              // columns per lane (strided; some invalid)

// ---------------------------------------------------------------------------
// Key packing: monotone map f64 -> u64 (unsigned order == float order), with
// the low 14 bits replaced by (col<<5)|p[col].  col in 1..300 (9 bits) sits
// ABOVE p (5 bits) so value-ties break on smaller col first (= np.argmin).
// Truncation perturbs dual arithmetic by ~1e-11 abs -- measure-zero vs the
// decision gaps of f32-derived costs.
// ---------------------------------------------------------------------------
__device__ __forceinline__ unsigned long long packkey(double v, int j, int p) {
    long long bb = __double_as_longlong(v);
    unsigned long long u = (bb < 0) ? ~(unsigned long long)bb
                                    : ((unsigned long long)bb | 0x8000000000000000ULL);
    return (u & ~16383ULL) | ((unsigned long long)(unsigned)j << 5)
                           | (unsigned long long)(unsigned)p;
}
__device__ __forceinline__ double unpackkey(unsigned long long key) {
    unsigned long long u = key & ~16383ULL;
    unsigned long long bb = (u & 0x8000000000000000ULL) ? (u & 0x7FFFFFFFFFFFFFFFULL)
                                                        : ~u;
    return __longlong_as_double((long long)bb);
}

// u64 min with partner from DPP lane swizzle (xor 1/2/4/8 within 16-lane rows)
template <int CTRL>
__device__ __forceinline__ unsigned long long dppmin(unsigned long long b) {
    int lo = __builtin_amdgcn_update_dpp(0, (int)(unsigned)b, CTRL, 0xF, 0xF, true);
    int hi = __builtin_amdgcn_update_dpp(0, (int)(unsigned)(b >> 32), CTRL, 0xF, 0xF, true);
    unsigned long long o = ((unsigned long long)(unsigned)hi << 32) | (unsigned)lo;
    return o < b ? o : b;
}
// xor16 within each 32-lane half via ds_swizzle BitMode (xor=16, and=0x1F)
__device__ __forceinline__ unsigned long long swz16min(unsigned long long b) {
    int lo = __builtin_amdgcn_ds_swizzle((int)(unsigned)b, 0x401F);
    int hi = __builtin_amdgcn_ds_swizzle((int)(unsigned)(b >> 32), 0x401F);
    unsigned long long o = ((unsigned long long)(unsigned)hi << 32) | (unsigned)lo;
    return o < b ? o : b;
}

__device__ __forceinline__ float giou_f(const float px[4], float parea,
                                        const float tx[4], float tarea) {
    float ltx = fmaxf(px[0], tx[0]), lty = fmaxf(px[1], tx[1]);
    float rbx = fminf(px[2], tx[2]), rby = fminf(px[3], tx[3]);
    float iw = fmaxf(rbx - ltx, 0.f), ih = fmaxf(rby - lty, 0.f);
    float inter = iw * ih;
    float uni = parea + tarea - inter;
    float iou = inter / uni;
    float lix = fminf(px[0], tx[0]), liy = fminf(px[1], tx[1]);
    float rix = fmaxf(px[2], tx[2]), riy = fmaxf(px[3], tx[3]);
    float aw = fmaxf(rix - lix, 0.f), ah = fmaxf(riy - liy, 0.f);
    float ai = aw * ah;
    return iou - (ai - uni) / ai;
}

__global__ __launch_bounds__(64) void fused_kernel(
        const float* __restrict__ logits,
        const float* __restrict__ pboxes,
        const int*   __restrict__ tlabels,
        const float* __restrict__ tboxes,
        double* __restrict__ accum) {
    const int b = blockIdx.x;
    const int tid = threadIdx.x;

    __shared__ float  costL[T_][Q_];     // 30000 B
    __shared__ float  lseL[Q_];
    __shared__ int    pL[Q_ + 1];
    __shared__ int    wayL[Q_ + 1];
    __shared__ double uL[T_ + 1];        // row duals (phase-start values)
    __shared__ int    mqL[T_];
    __shared__ int    lblL[T_];
    __shared__ int    lblq[Q_];
    __shared__ float  tbL[T_][4];        // cxcywh
    __shared__ float  txL[T_][4];        // xyxy
    __shared__ float  taL[T_];

    // ---- preload targets ----
    if (tid < T_) {
        lblL[tid] = tlabels[b * T_ + tid];
        float c0 = tboxes[(size_t)(b * T_ + tid) * 4 + 0];
        float c1 = tboxes[(size_t)(b * T_ + tid) * 4 + 1];
        float c2 = tboxes[(size_t)(b * T_ + tid) * 4 + 2];
        float c3 = tboxes[(size_t)(b * T_ + tid) * 4 + 3];
        tbL[tid][0] = c0; tbL[tid][1] = c1; tbL[tid][2] = c2; tbL[tid][3] = c3;
        float x0 = c0 - 0.5f * c2, y0 = c1 - 0.5f * c3;
        float x1 = c0 + 0.5f * c2, y1 = c1 + 0.5f * c3;
        txL[tid][0] = x0; txL[tid][1] = y0; txL[tid][2] = x1; txL[tid][3] = y1;
        taL[tid] = (x1 - x0) * (y1 - y0);
    }
    for (int j = tid; j <= Q_; j += 64) { pL[j] = 0; wayL[j] = 0; }
    if (tid <= T_) uL[tid] = 0.0;
    __syncthreads();

    const float* lgb = logits + (size_t)b * Q_ * L_;
    const float* pbb = pboxes + (size_t)b * Q_ * 4;

    // ---- cost build (into LDS); logit row cached in registers ----
    for (int q = tid; q < Q_; q += 64) {
        const float4* lr4 = (const float4*)(lgb + (size_t)q * L_);  // 92 = 23*4
        float4 r[23];
#pragma unroll
        for (int c = 0; c < 23; ++c) r[c] = lr4[c];
        float m0 = -INFINITY, m1 = -INFINITY, m2 = -INFINITY, m3 = -INFINITY;
#pragma unroll
        for (int c = 0; c < 23; ++c) {
            m0 = fmaxf(m0, r[c].x); m1 = fmaxf(m1, r[c].y);
            m2 = fmaxf(m2, r[c].z); m3 = fmaxf(m3, r[c].w);
        }
        float mx = fmaxf(fmaxf(m0, m1), fmaxf(m2, m3));
        float s0 = 0.f, s1 = 0.f, s2 = 0.f, s3 = 0.f;
#pragma unroll
        for (int c = 0; c < 23; ++c) {
            s0 += expf(r[c].x - mx); s1 += expf(r[c].y - mx);
            s2 += expf(r[c].z - mx); s3 += expf(r[c].w - mx);
        }
        float lz = mx + logf((s0 + s1) + (s2 + s3));
        lseL[q] = lz;

        float p0 = pbb[(size_t)q * 4 + 0], p1 = pbb[(size_t)q * 4 + 1];
        float p2 = pbb[(size_t)q * 4 + 2], p3 = pbb[(size_t)q * 4 + 3];
        float px[4] = { p0 - 0.5f * p2, p1 - 0.5f * p3, p0 + 0.5f * p2, p1 + 0.5f * p3 };
        float parea = (px[2] - px[0]) * (px[3] - px[1]);

        for (int t = 0; t < T_; ++t) {
            float cls = lz - lgb[(size_t)q * L_ + lblL[t]];
            float l1 = fabsf(p0 - tbL[t][0]) + fabsf(p1 - tbL[t][1]) +
                       fabsf(p2 - tbL[t][2]) + fabsf(p3 - tbL[t][3]);
            float tx[4] = { txL[t][0], txL[t][1], txL[t][2], txL[t][3] };
            float g = giou_f(px, parea, tx, taL[t]);
            costL[t][q] = C_BB * l1 + cls - C_GI * g;
        }
    }
    __syncthreads();

    // ---- Jonker-Volgenant, invariant-minv' formulation, key-packed reduce ----
    double v0[K_], minv[K_], stampv[K_];
    int pReg[K_];
    bool usedk[K_], validk[K_];
#pragma unroll
    for (int k = 0; k < K_; ++k) {
        validk[k] = (tid + 64 * k) < Q_;
        v0[k] = 0.0; pReg[k] = 0; stampv[k] = 0.0;
        usedk[k] = false; minv[k] = INFINITY;
    }

    for (int i = 1; i <= T_; ++i) {
        if (tid == 0) pL[0] = i;
#pragma unroll
        for (int k = 0; k < K_; ++k) { minv[k] = INFINITY; usedk[k] = false; }
        double S = 0.0;
        int j0 = 0, i0 = i;
        double u0i0 = 0.0;          // u[i] == 0: row i is free

        while (true) {
            double a = u0i0 - S;
            const float* crow = &costL[i0 - 1][0];
#pragma unroll
            for (int k = 0; k < K_; ++k) {
                if (validk[k] && !usedk[k]) {
                    int col = tid + 64 * k;
                    double cur = (double)crow[col] - a - v0[k];
                    if (cur < minv[k]) { minv[k] = cur; wayL[col + 1] = j0; }
                }
            }
            unsigned long long best = ~0ULL;
#pragma unroll
            for (int k = 0; k < K_; ++k) {
                if (validk[k] && !usedk[k]) {
                    unsigned long long pk = packkey(minv[k], tid + 1 + 64 * k, pReg[k]);
                    if (pk < best) best = pk;
                }
            }
            // 6-stage wave min-reduce: shfl32 -> swizzle16 -> DPP 8/4/2/1
            { unsigned long long o = __shfl_xor(best, 32); if (o < best) best = o; }
            best = swz16min(best);
            best = dppmin<0x140>(best);   // row_mirror  (xor 8)
            best = dppmin<0x141>(best);   // row_half_mirror (xor 4)
            best = dppmin<0x4E>(best);    // quad_perm [2,3,0,1] (xor 2)
            best = dppmin<0xB1>(best);    // quad_perm [1,0,3,2] (xor 1)

            int j1  = (int)((best >> 5) & 511ULL);
            int i0n = (int)(best & 31ULL);
            double Snew = unpackkey(best);
            S = Snew;
            j0 = j1;
            if (i0n == 0) break;          // reached a free column
            int owner = (j1 - 1) & 63, k1 = (j1 - 1) >> 6;
            if (tid == owner) {
#pragma unroll
                for (int k = 0; k < K_; ++k)
                    if (k == k1) { usedk[k] = true; stampv[k] = Snew; }
            }
            i0 = i0n;
            u0i0 = uL[i0];                // broadcast read; phase-start value
        }

        // phase-end dual updates (pre-augment p; distinct rows per lane)
#pragma unroll
        for (int k = 0; k < K_; ++k) {
            if (validk[k] && usedk[k]) {
                double d = S - stampv[k];
                v0[k] -= d;
                uL[pReg[k]] += d;
            }
        }
        if (tid == 0) uL[i] += S;         // virtual column 0 (row i)
        __syncthreads();
        if (tid == 0) {                   // augment
            int jj = j0;
            while (jj) { int jn = wayL[jj]; pL[jj] = pL[jn]; jj = jn; }
        }
        __syncthreads();
#pragma unroll
        for (int k = 0; k < K_; ++k)
            if (validk[k]) pReg[k] = pL[tid + 1 + 64 * k];
    }

    // ---- matching -> per-target query, per-query label ----
#pragma unroll
    for (int k = 0; k < K_; ++k)
        if (validk[k] && pReg[k] > 0) mqL[pReg[k] - 1] = tid + 64 * k;
    for (int q = tid; q < Q_; q += 64) lblq[q] = NCLS;
    __syncthreads();
    if (tid < T_) lblq[mqL[tid]] = lblL[tid];
    __syncthreads();

    // ---- losses ----
    double ce = 0.0, sb = 0.0, sg = 0.0;
    for (int q = tid; q < Q_; q += 64) {
        int label = lblq[q];
        float nll = lseL[q] - lgb[(size_t)q * L_ + label];
        float w = (label == NCLS) ? EOS : 1.0f;
        ce += (double)(w * nll);
    }
    if (tid < T_) {
        int q = mqL[tid];
        float p0 = pbb[(size_t)q * 4 + 0], p1 = pbb[(size_t)q * 4 + 1];
        float p2 = pbb[(size_t)q * 4 + 2], p3 = pbb[(size_t)q * 4 + 3];
        sb = (double)(fabsf(p0 - tbL[tid][0]) + fabsf(p1 - tbL[tid][1]) +
                      fabsf(p2 - tbL[tid][2]) + fabsf(p3 - tbL[tid][3]));
        float px[4] = { p0 - 0.5f * p2, p1 - 0.5f * p3, p0 + 0.5f * p2, p1 + 0.5f * p3 };
        float parea = (px[2] - px[0]) * (px[3] - px[1]);
        float tx[4] = { txL[tid][0], txL[tid][1], txL[tid][2], txL[tid][3] };
        float g = giou_f(px, parea, tx, taL[tid]);
        sg = (double)(1.0f - g);
    }
#pragma unroll
    for (int off = 1; off < 64; off <<= 1) {
        ce += __shfl_xor(ce, off);
        sb += __shfl_xor(sb, off);
        sg += __shfl_xor(sg, off);
    }
    if (tid == 0) {
        atomicAdd(&accum[0], ce);
        atomicAdd(&accum[1], sb);
        atomicAdd(&accum[2], sg);
    }
}

__global__ void finalize_kernel(const double* __restrict__ accum,
                                float* __restrict__ out) {
    if (threadIdx.x == 0 && blockIdx.x == 0) {
        // w.sum() = 64*(25*1.0 + 275*0.1) = 3360 ; num_t = 64*25 = 1600
        float lce = W_CE * (float)(accum[0] / 3360.0);
        float lbb = W_BBOX * (float)(accum[1] / 1600.0);
        float lgi = W_GIOU * (float)(accum[2] / 1600.0);
        out[0] = lce;
        out[1] = lbb;
        out[2] = lgi;
        out[3] = lce + lbb + lgi;
    }
}

extern "C" void kernel_launch(void* const* d_in, const int* in_sizes, int n_in,
                              void* d_out, int out_size, void* d_ws, size_t ws_size,
                              hipStream_t stream) {
    (void)in_sizes; (void)n_in; (void)out_size; (void)ws_size;
    const float* logits  = (const float*)d_in[0];   // [B,Q,92] f32
    const float* pboxes  = (const float*)d_in[1];   // [B,Q,4]  f32
    const int*   tlabels = (const int*)d_in[2];     // [B,T]    i32
    const float* tboxes  = (const float*)d_in[3];   // [B,T,4]  f32
    float* out = (float*)d_out;
    double* accum = (double*)d_ws;

    hipMemsetAsync(d_ws, 0, 64, stream);
    fused_kernel<<<B_, 64, 0, stream>>>(logits, pboxes, tlabels, tboxes, accum);
    finalize_kernel<<<1, 64, 0, stream>>>(accum, out);
}

// Round 4
// 36.236 us; speedup vs baseline: 3.6367x; 2.2080x over previous
//
#include <hip/hip_runtime.h>
#include <math.h>

constexpr int B_ = 64;
constexpr int Q_ = 300;
constexpr int T_ = 25;
constexpr int NCLS = 91;
constexpr int L_ = NCLS + 1;       // 92
constexpr float C_BB = 5.0f, C_GI = 2.0f;
constexpr float W_CE = 2.0f, W_BBOX = 2.5f, W_GIOU = 2.0f;
constexpr float EOS = 0.1f;
constexpr int K_ = 5;              // columns per lane in JV (wave 0)
constexpr int TPB = 256;           // 4 waves

// ---------------------------------------------------------------------------
// f64 -> ordered u64, low 14 bits = (col<<5)|p[col]; col 1..300, p 0..25.
// Unsigned order == float order; ties break on smaller col (= np.argmin).
// ---------------------------------------------------------------------------
__device__ __forceinline__ unsigned long long packkey(double v, int j, int p) {
    long long bb = __double_as_longlong(v);
    unsigned long long u = (bb < 0) ? ~(unsigned long long)bb
                                    : ((unsigned long long)bb | 0x8000000000000000ULL);
    return (u & ~16383ULL) | ((unsigned long long)(unsigned)j << 5)
                           | (unsigned long long)(unsigned)p;
}
__device__ __forceinline__ double unpackkey(unsigned long long key) {
    unsigned long long u = key & ~16383ULL;
    unsigned long long bb = (u & 0x8000000000000000ULL) ? (u & 0x7FFFFFFFFFFFFFFFULL)
                                                        : ~u;
    return __longlong_as_double((long long)bb);
}
// f32 <-> ordered u32 (exact, for greedy row minima)
__device__ __forceinline__ unsigned int ord32(float f) {
    unsigned int b = __float_as_uint(f);
    return (b & 0x80000000u) ? ~b : (b | 0x80000000u);
}
__device__ __forceinline__ float unord32(unsigned int o) {
    unsigned int b = (o & 0x80000000u) ? (o & 0x7FFFFFFFu) : ~o;
    return __uint_as_float(b);
}

template <int CTRL>
__device__ __forceinline__ unsigned long long dppmin(unsigned long long b) {
    int lo = __builtin_amdgcn_update_dpp(0, (int)(unsigned)b, CTRL, 0xF, 0xF, true);
    int hi = __builtin_amdgcn_update_dpp(0, (int)(unsigned)(b >> 32), CTRL, 0xF, 0xF, true);
    unsigned long long o = ((unsigned long long)(unsigned)hi << 32) | (unsigned)lo;
    return o < b ? o : b;
}
__device__ __forceinline__ unsigned long long swz16min(unsigned long long b) {
    int lo = __builtin_amdgcn_ds_swizzle((int)(unsigned)b, 0x401F);
    int hi = __builtin_amdgcn_ds_swizzle((int)(unsigned)(b >> 32), 0x401F);
    unsigned long long o = ((unsigned long long)(unsigned)hi << 32) | (unsigned)lo;
    return o < b ? o : b;
}

__device__ __forceinline__ float giou_f(const float px[4], float parea,
                                        const float tx[4], float tarea) {
    float ltx = fmaxf(px[0], tx[0]), lty = fmaxf(px[1], tx[1]);
    float rbx = fminf(px[2], tx[2]), rby = fminf(px[3], tx[3]);
    float iw = fmaxf(rbx - ltx, 0.f), ih = fmaxf(rby - lty, 0.f);
    float inter = iw * ih;
    float uni = parea + tarea - inter;
    float iou = inter / uni;
    float lix = fminf(px[0], tx[0]), liy = fminf(px[1], tx[1]);
    float rix = fmaxf(px[2], tx[2]), riy = fmaxf(px[3], tx[3]);
    float aw = fmaxf(rix - lix, 0.f), ah = fmaxf(riy - liy, 0.f);
    float ai = aw * ah;
    return iou - (ai - uni) / ai;
}

__global__ __launch_bounds__(TPB) void fused_kernel(
        const float* __restrict__ logits,
        const float* __restrict__ pboxes,
        const int*   __restrict__ tlabels,
        const float* __restrict__ tboxes,
        double* __restrict__ partial) {
    const int b = blockIdx.x;
    const int tid = threadIdx.x;

    __shared__ float  costL[T_][Q_];                 // 30000 B
    __shared__ float  lseL[Q_];
    __shared__ unsigned long long keysL[T_][TPB + 1];// 51.4 KB
    __shared__ unsigned long long key2L[T_][8];
    __shared__ int    pL[Q_ + 1];
    __shared__ int    wayL[Q_ + 1];
    __shared__ double uL[T_ + 1];
    __shared__ int    argcolL[T_];
    __shared__ int    mqL[T_];
    __shared__ int    lblL[T_];
    __shared__ int    lblq[Q_];
    __shared__ float  tbL[T_][4];
    __shared__ float  txL[T_][4];
    __shared__ float  taL[T_];
    __shared__ double wsum[4][3];

    // ---- preload targets + init ----
    if (tid < T_) {
        lblL[tid] = tlabels[b * T_ + tid];
        float c0 = tboxes[(size_t)(b * T_ + tid) * 4 + 0];
        float c1 = tboxes[(size_t)(b * T_ + tid) * 4 + 1];
        float c2 = tboxes[(size_t)(b * T_ + tid) * 4 + 2];
        float c3 = tboxes[(size_t)(b * T_ + tid) * 4 + 3];
        tbL[tid][0] = c0; tbL[tid][1] = c1; tbL[tid][2] = c2; tbL[tid][3] = c3;
        float x0 = c0 - 0.5f * c2, y0 = c1 - 0.5f * c3;
        float x1 = c0 + 0.5f * c2, y1 = c1 + 0.5f * c3;
        txL[tid][0] = x0; txL[tid][1] = y0; txL[tid][2] = x1; txL[tid][3] = y1;
        taL[tid] = (x1 - x0) * (y1 - y0);
    }
    for (int j = tid; j <= Q_; j += TPB) { pL[j] = 0; wayL[j] = 0; }
    for (int q = tid; q < Q_; q += TPB) lblq[q] = NCLS;
    __syncthreads();

    const float* lgb = logits + (size_t)b * Q_ * L_;
    const float* pbb = pboxes + (size_t)b * Q_ * 4;

    // ---- cost build (all 4 waves), fused per-row min tracking ----
    unsigned long long key[T_];
#pragma unroll
    for (int t = 0; t < T_; ++t) key[t] = ~0ULL;

    for (int q = tid; q < Q_; q += TPB) {
        const float4* lr4 = (const float4*)(lgb + (size_t)q * L_);  // 92 = 23*4
        float m0 = -INFINITY, m1 = -INFINITY, m2 = -INFINITY, m3 = -INFINITY;
        for (int c = 0; c < 23; ++c) {
            float4 v = lr4[c];
            m0 = fmaxf(m0, v.x); m1 = fmaxf(m1, v.y);
            m2 = fmaxf(m2, v.z); m3 = fmaxf(m3, v.w);
        }
        float mx = fmaxf(fmaxf(m0, m1), fmaxf(m2, m3));
        float s0 = 0.f, s1 = 0.f, s2 = 0.f, s3 = 0.f;
        for (int c = 0; c < 23; ++c) {
            float4 v = lr4[c];
            s0 += expf(v.x - mx); s1 += expf(v.y - mx);
            s2 += expf(v.z - mx); s3 += expf(v.w - mx);
        }
        float lz = mx + logf((s0 + s1) + (s2 + s3));
        lseL[q] = lz;

        float p0 = pbb[(size_t)q * 4 + 0], p1 = pbb[(size_t)q * 4 + 1];
        float p2 = pbb[(size_t)q * 4 + 2], p3 = pbb[(size_t)q * 4 + 3];
        float px[4] = { p0 - 0.5f * p2, p1 - 0.5f * p3, p0 + 0.5f * p2, p1 + 0.5f * p3 };
        float parea = (px[2] - px[0]) * (px[3] - px[1]);

#pragma unroll
        for (int t = 0; t < T_; ++t) {
            float cls = lz - lgb[(size_t)q * L_ + lblL[t]];
            float l1 = fabsf(p0 - tbL[t][0]) + fabsf(p1 - tbL[t][1]) +
                       fabsf(p2 - tbL[t][2]) + fabsf(p3 - tbL[t][3]);
            float tx[4] = { txL[t][0], txL[t][1], txL[t][2], txL[t][3] };
            float g = giou_f(px, parea, tx, taL[t]);
            float cost = C_BB * l1 + cls - C_GI * g;
            costL[t][q] = cost;
            unsigned long long kq =
                ((unsigned long long)ord32(cost) << 32) | (unsigned)q;
            if (kq < key[t]) key[t] = kq;
        }
    }
#pragma unroll
    for (int t = 0; t < T_; ++t) keysL[t][tid] = key[t];
    __syncthreads();

    // ---- row-min reduce stage 2: 200 threads x 32 entries ----
    if (tid < 200) {
        int row = tid >> 3, c = tid & 7;
        unsigned long long best = ~0ULL;
        for (int j = 0; j < 32; ++j) {
            unsigned long long k = keysL[row][c * 32 + j];
            if (k < best) best = k;
        }
        key2L[row][c] = best;
    }
    __syncthreads();

    // =====================================================================
    // Wave 0 only: greedy init + JV phases for collided rows. NO barriers
    // inside (single wave; LDS ops are in-order within a wave).
    // =====================================================================
    if (tid < 64) {
        // stage 3: exact row minima + greedy proposals
        if (tid < T_) {
            unsigned long long rk = ~0ULL;
#pragma unroll
            for (int j = 0; j < 8; ++j) {
                unsigned long long k = key2L[tid][j];
                if (k < rk) rk = k;
            }
            argcolL[tid] = (int)(rk & 0xFFFFFFFFULL);          // 0-based col
            uL[tid + 1] = (double)unord32((unsigned)(rk >> 32)); // exact min
        }
        // conflict resolution: row wins iff it is the smallest proposer
        int win = tid;
        if (tid < T_) {
            int myc = argcolL[tid];
            for (int j = 0; j < T_; ++j) {
                int oc = argcolL[j];
                if (oc == myc && j < win) win = j;
            }
            if (win == tid) pL[myc + 1] = tid + 1;
        }
        unsigned long long matchmask = __ballot(tid < T_ && win == tid);

        // per-lane column state
        double v0[K_], minv[K_], stampv[K_];
        int pReg[K_];
        bool usedk[K_], validk[K_];
#pragma unroll
        for (int k = 0; k < K_; ++k) {
            int col = tid + 64 * k;
            validk[k] = col < Q_;
            v0[k] = 0.0; stampv[k] = 0.0; usedk[k] = false; minv[k] = INFINITY;
            pReg[k] = validk[k] ? pL[col + 1] : 0;
        }

        // shortest-augmenting-path phases for unmatched rows only
        for (int i = 1; i <= T_; ++i) {
            if (matchmask & (1ULL << (i - 1))) continue;
            if (tid == 0) pL[0] = i;
#pragma unroll
            for (int k = 0; k < K_; ++k) { minv[k] = INFINITY; usedk[k] = false; }
            double S = 0.0;
            int j0 = 0, i0 = i;
            double u0i0 = uL[i];           // phase-start dual of the free row

            for (int step = 0; step < 512; ++step) {
                double a = u0i0 - S;
                const float* crow = &costL[i0 - 1][0];
#pragma unroll
                for (int k = 0; k < K_; ++k) {
                    if (validk[k] && !usedk[k]) {
                        int col = tid + 64 * k;
                        double cur = (double)crow[col] - a - v0[k];
                        if (cur < minv[k]) { minv[k] = cur; wayL[col + 1] = j0; }
                    }
                }
                unsigned long long best = ~0ULL;
#pragma unroll
                for (int k = 0; k < K_; ++k) {
                    if (validk[k] && !usedk[k]) {
                        unsigned long long pk =
                            packkey(minv[k], tid + 1 + 64 * k, pReg[k]);
                        if (pk < best) best = pk;
                    }
                }
                { unsigned long long o = __shfl_xor(best, 32); if (o < best) best = o; }
                best = swz16min(best);
                best = dppmin<0x140>(best);   // xor 8
                best = dppmin<0x141>(best);   // xor 4
                best = dppmin<0x4E>(best);    // xor 2
                best = dppmin<0xB1>(best);    // xor 1

                int j1  = (int)((best >> 5) & 511ULL);
                int i0n = (int)(best & 31ULL);
                double Snew = unpackkey(best);
                S = Snew;
                j0 = j1;
                if (i0n == 0) break;
                int owner = (j1 - 1) & 63, k1 = (j1 - 1) >> 6;
                if (tid == owner) {
#pragma unroll
                    for (int k = 0; k < K_; ++k)
                        if (k == k1) { usedk[k] = true; stampv[k] = Snew; }
                }
                i0 = i0n;
                u0i0 = uL[i0];
            }

            // phase-end dual updates (pre-augment p; distinct rows per lane)
#pragma unroll
            for (int k = 0; k < K_; ++k) {
                if (validk[k] && usedk[k]) {
                    double d = S - stampv[k];
                    v0[k] -= d;
                    uL[pReg[k]] += d;
                }
            }
            if (tid == 0) {
                uL[i] += S;
                int jj = j0;                  // augment
                while (jj) { int jn = wayL[jj]; pL[jj] = pL[jn]; jj = jn; }
            }
#pragma unroll
            for (int k = 0; k < K_; ++k)
                if (validk[k]) pReg[k] = pL[tid + 1 + 64 * k];
        }

        // matching -> per-target query, per-query label
#pragma unroll
        for (int k = 0; k < K_; ++k)
            if (validk[k] && pReg[k] > 0) mqL[pReg[k] - 1] = tid + 64 * k;
        if (tid < T_) lblq[mqL[tid]] = lblL[tid];
    }
    __syncthreads();

    // ---- losses (all 4 waves) ----
    double ce = 0.0, sb = 0.0, sg = 0.0;
    for (int q = tid; q < Q_; q += TPB) {
        int label = lblq[q];
        float nll = lseL[q] - lgb[(size_t)q * L_ + label];
        float w = (label == NCLS) ? EOS : 1.0f;
        ce += (double)(w * nll);
    }
    if (tid < T_) {
        int q = mqL[tid];
        float p0 = pbb[(size_t)q * 4 + 0], p1 = pbb[(size_t)q * 4 + 1];
        float p2 = pbb[(size_t)q * 4 + 2], p3 = pbb[(size_t)q * 4 + 3];
        sb = (double)(fabsf(p0 - tbL[tid][0]) + fabsf(p1 - tbL[tid][1]) +
                      fabsf(p2 - tbL[tid][2]) + fabsf(p3 - tbL[tid][3]));
        float px[4] = { p0 - 0.5f * p2, p1 - 0.5f * p3, p0 + 0.5f * p2, p1 + 0.5f * p3 };
        float parea = (px[2] - px[0]) * (px[3] - px[1]);
        float tx[4] = { txL[tid][0], txL[tid][1], txL[tid][2], txL[tid][3] };
        float g = giou_f(px, parea, tx, taL[tid]);
        sg = (double)(1.0f - g);
    }
#pragma unroll
    for (int off = 1; off < 64; off <<= 1) {
        ce += __shfl_xor(ce, off);
        sb += __shfl_xor(sb, off);
        sg += __shfl_xor(sg, off);
    }
    if ((tid & 63) == 0) {
        int w = tid >> 6;
        wsum[w][0] = ce; wsum[w][1] = sb; wsum[w][2] = sg;
    }
    __syncthreads();
    if (tid == 0) {
        double a0 = 0, a1 = 0, a2 = 0;
        for (int w = 0; w < 4; ++w) { a0 += wsum[w][0]; a1 += wsum[w][1]; a2 += wsum[w][2]; }
        partial[(size_t)b * 3 + 0] = a0;
        partial[(size_t)b * 3 + 1] = a1;
        partial[(size_t)b * 3 + 2] = a2;
    }
}

__global__ __launch_bounds__(64) void finalize_kernel(const double* __restrict__ partial,
                                                      float* __restrict__ out) {
    int tid = threadIdx.x;
    double a = partial[(size_t)tid * 3 + 0];
    double c = partial[(size_t)tid * 3 + 1];
    double g = partial[(size_t)tid * 3 + 2];
#pragma unroll
    for (int off = 1; off < 64; off <<= 1) {
        a += __shfl_xor(a, off);
        c += __shfl_xor(c, off);
        g += __shfl_xor(g, off);
    }
    if (tid == 0) {
        // w.sum() = 64*(25*1.0 + 275*0.1) = 3360 ; num_t = 64*25 = 1600
        float lce = W_CE * (float)(a / 3360.0);
        float lbb = W_BBOX * (float)(c / 1600.0);
        float lgi = W_GIOU * (float)(g / 1600.0);
        out[0] = lce;
        out[1] = lbb;
        out[2] = lgi;
        out[3] = lce + lbb + lgi;
    }
}

extern "C" void kernel_launch(void* const* d_in, const int* in_sizes, int n_in,
                              void* d_out, int out_size, void* d_ws, size_t ws_size,
                              hipStream_t stream) {
    (void)in_sizes; (void)n_in; (void)out_size; (void)ws_size;
    const float* logits  = (const float*)d_in[0];   // [B,Q,92] f32
    const float* pboxes  = (const float*)d_in[1];   // [B,Q,4]  f32
    const int*   tlabels = (const int*)d_in[2];     // [B,T]    i32
    const float* tboxes  = (const float*)d_in[3];   // [B,T,4]  f32
    float* out = (float*)d_out;
    double* partial = (double*)d_ws;                // [64][3] f64

    fused_kernel<<<B_, TPB, 0, stream>>>(logits, pboxes, tlabels, tboxes, partial);
    finalize_kernel<<<1, 64, 0, stream>>>(partial, out);
}